// Round 3
// baseline (167.843 us; speedup 1.0000x reference)
//
#include <hip/hip_runtime.h>

// TripletAngularMarginLoss: bs=16384, d=64 (== number of classes)
// out = mean(relu(0.5 + ap - an)) + mean(relu(0.8-ap)) + mean(relu(an-0.4)) + CE
// ap[i] = min_{t[j]==t[i]} cos(x_i,x_j), an[i] = max_{t[j]!=t[i]} cos(x_i,x_j)
//
// R2 insight: mine was VALU-bound (72% VALUBusy, 14% MfmaUtil) on the 5-op
// masked min/max epilogue. Fix: sort rows by class -> positives of a wave's
// 64 rows form ONE column interval [lo,hi); groups outside it are pure
// negative -> 1 max/entry. Means are permutation-invariant so no un-sort.

#define N_ROWS 16384
#define N_DIM 64

typedef __attribute__((ext_vector_type(8))) short bf16x8;
typedef __attribute__((ext_vector_type(4))) float f32x4;

__device__ inline unsigned short f2bf(float f) {
  unsigned u = __float_as_uint(f);
  unsigned r = u + 0x7fffu + ((u >> 16) & 1u);   // round-to-nearest-even
  return (unsigned short)(r >> 16);
}

// order-preserving float->uint encoding for atomicMin/atomicMax
__device__ inline unsigned enc_key(float f) {
  unsigned u = __float_as_uint(f);
  return (u & 0x80000000u) ? ~u : (u | 0x80000000u);
}
__device__ inline float dec_key(unsigned k) {
  unsigned u = (k & 0x80000000u) ? (k ^ 0x80000000u) : ~k;
  return __uint_as_float(u);
}

// ---------------- Kernel 0: class histogram -> prefix -> scatter positions --
// Single block, 1024 threads. Also inits mp/mn key arrays (replaces memsets).
__global__ void perm_kernel(const int* __restrict__ tgt, int* __restrict__ perm,
                            int* __restrict__ ts, int* __restrict__ class_start,
                            unsigned* __restrict__ mp_key, unsigned* __restrict__ mn_key) {
  __shared__ int hist[64];
  __shared__ int start[65];
  __shared__ int cursor[64];
  const int tid = threadIdx.x;
  if (tid < 64) hist[tid] = 0;
  // init the min/max accumulator keys (ws is poisoned 0xAA before each launch)
  for (int i = tid; i < N_ROWS; i += 1024) { mp_key[i] = 0xFFFFFFFFu; mn_key[i] = 0u; }
  __syncthreads();
  int c[16];
#pragma unroll
  for (int k = 0; k < 16; ++k) {
    c[k] = tgt[tid + k * 1024];
    atomicAdd(&hist[c[k]], 1);
  }
  __syncthreads();
  if (tid < 64) {
    int s = 0;
    for (int j = 0; j < tid; ++j) s += hist[j];
    start[tid] = s; cursor[tid] = s; class_start[tid] = s;
    if (tid == 63) { start[64] = s + hist[63]; class_start[64] = s + hist[63]; }
  }
  __syncthreads();
#pragma unroll
  for (int k = 0; k < 16; ++k) {
    const int r = tid + k * 1024;
    const int pos = atomicAdd(&cursor[c[k]], 1);
    perm[r] = pos;
    ts[pos] = c[k];
  }
}

// ---------------- Kernel 1: normalize, CE term, write bf16 row to sorted slot
__global__ void prep_kernel(const float* __restrict__ x, const int* __restrict__ tgt,
                            const int* __restrict__ perm,
                            unsigned short* __restrict__ xs, float* __restrict__ ce_row) {
  const int row  = blockIdx.x * 4 + (threadIdx.x >> 6);
  const int lane = threadIdx.x & 63;
  float v  = x[row * N_DIM + lane];
  float ss = v * v;
#pragma unroll
  for (int s = 1; s < 64; s <<= 1) ss += __shfl_xor(ss, s, 64);
  float xn = v * rsqrtf(ss);
  xs[perm[row] * N_DIM + lane] = f2bf(xn);

  // log-softmax over the 64 normalized features
  float mx = xn;
#pragma unroll
  for (int s = 1; s < 64; s <<= 1) mx = fmaxf(mx, __shfl_xor(mx, s, 64));
  float e  = __expf(xn - mx);
  float se = e;
#pragma unroll
  for (int s = 1; s < 64; s <<= 1) se += __shfl_xor(se, s, 64);
  float lse = mx + __logf(se);
  int   t   = tgt[row];                 // wave-uniform
  float xt  = __shfl(xn, t, 64);
  if (lane == 0) ce_row[row] = lse - xt;
}

// ---------------- Kernel 2: MFMA similarity + hard mining (sorted layout) ----
// grid = 64 i-blocks * 32 j-splits = 2048 blocks of 256 threads (4 waves).
// Wave: 64 sorted i-rows, A register-resident, sweeps 512 cols in 16-col groups.
// Wave-uniform fast path (group outside [lo,hi)): pure-negative, 1 max/entry.
__global__ void mine_kernel(const unsigned short* __restrict__ xs, const int* __restrict__ ts,
                            const int* __restrict__ class_start,
                            unsigned* __restrict__ mp_key, unsigned* __restrict__ mn_key) {
  const int lane    = threadIdx.x & 63;
  const int wv      = threadIdx.x >> 6;
  const int iblk    = blockIdx.x >> 5;
  const int jspl    = blockIdx.x & 31;
  const int rowbase = iblk * 256 + wv * 64;
  const int m = lane & 15, q = lane >> 4;

  // A fragments: lane holds row (rowbase+tr*16+m), k = q*8..q*8+7 (+32)
  bf16x8 a[4][2];
#pragma unroll
  for (int tr = 0; tr < 4; ++tr) {
    const unsigned short* p = xs + (rowbase + tr * 16 + m) * N_DIM + q * 8;
    a[tr][0] = *(const bf16x8*)(p);
    a[tr][1] = *(const bf16x8*)(p + 32);
  }
  // classes of this lane's C/D rows (row = tr*16 + q*4 + r) — slow path only
  int ti[4][4];
#pragma unroll
  for (int tr = 0; tr < 4; ++tr)
#pragma unroll
    for (int r = 0; r < 4; ++r)
      ti[tr][r] = ts[rowbase + tr * 16 + q * 4 + r];

  // positive-column interval for ALL rows of this wave (rows sorted by class)
  const int cmin = ts[rowbase];
  const int cmax = ts[rowbase + 63];
  const int lo   = class_start[cmin];
  const int hi   = class_start[cmax + 1];

  float mp[16], mn[16];
#pragma unroll
  for (int k = 0; k < 16; ++k) { mp[k] = __builtin_inff(); mn[k] = -__builtin_inff(); }

  const int jbase = jspl * 512;

  // prologue: load column group jc=0
  const unsigned short* p0 = xs + (jbase + m) * N_DIM + q * 8;
  bf16x8 b0 = *(const bf16x8*)p0;
  bf16x8 b1 = *(const bf16x8*)(p0 + 32);

  for (int jc = 0; jc < 32; ++jc) {
    bf16x8 cb0 = b0, cb1 = b1;
    const int jb = jbase + jc * 16;
    if (jc < 31) {                       // distance-1 prefetch
      const unsigned short* np = xs + (jb + 16 + m) * N_DIM + q * 8;
      b0 = *(const bf16x8*)np;
      b1 = *(const bf16x8*)(np + 32);
    }
    const bool slow = (jb < hi) && (jb + 16 > lo);   // wave-uniform
    if (slow) {
      const int ctj = ts[jb + m];        // class of this lane's column
#pragma unroll
      for (int tr = 0; tr < 4; ++tr) {
        f32x4 acc = {0.f, 0.f, 0.f, 0.f};
        acc = __builtin_amdgcn_mfma_f32_16x16x32_bf16(a[tr][0], cb0, acc, 0, 0, 0);
        acc = __builtin_amdgcn_mfma_f32_16x16x32_bf16(a[tr][1], cb1, acc, 0, 0, 0);
#pragma unroll
        for (int r = 0; r < 4; ++r) {
          const bool  pos = (ctj == ti[tr][r]);
          const float d   = acc[r];
          const int   k   = tr * 4 + r;
          mp[k] = fminf(mp[k], pos ? d : __builtin_inff());
          mn[k] = fmaxf(mn[k], pos ? -__builtin_inff() : d);
        }
      }
    } else {                              // pure-negative fast path: 1 op/entry
#pragma unroll
      for (int tr = 0; tr < 4; ++tr) {
        f32x4 acc = {0.f, 0.f, 0.f, 0.f};
        acc = __builtin_amdgcn_mfma_f32_16x16x32_bf16(a[tr][0], cb0, acc, 0, 0, 0);
        acc = __builtin_amdgcn_mfma_f32_16x16x32_bf16(a[tr][1], cb1, acc, 0, 0, 0);
#pragma unroll
        for (int r = 0; r < 4; ++r)
          mn[tr * 4 + r] = fmaxf(mn[tr * 4 + r], acc[r]);
      }
    }
  }

  // reduce across the 16 m-lanes inside each q-group
#pragma unroll
  for (int s = 1; s < 16; s <<= 1) {
#pragma unroll
    for (int k = 0; k < 16; ++k) {
      mp[k] = fminf(mp[k], __shfl_xor(mp[k], s, 64));
      mn[k] = fmaxf(mn[k], __shfl_xor(mn[k], s, 64));
    }
  }
  if (m == 0) {
#pragma unroll
    for (int tr = 0; tr < 4; ++tr)
#pragma unroll
      for (int r = 0; r < 4; ++r) {
        const int row = rowbase + tr * 16 + q * 4 + r;
        atomicMin(&mp_key[row], enc_key(mp[tr * 4 + r]));
        atomicMax(&mn_key[row], enc_key(mn[tr * 4 + r]));
      }
  }
}

// ---------------- Kernel 3: final reduction (1024 threads, 16 waves) ---------
__global__ void finalize_kernel(const unsigned* __restrict__ mp_key, const unsigned* __restrict__ mn_key,
                                const float* __restrict__ ce_row, float* __restrict__ out) {
  __shared__ float red[4][16];
  float s1 = 0.f, s2 = 0.f, s3 = 0.f, s4 = 0.f;
  for (int r = threadIdx.x; r < N_ROWS; r += 1024) {
    float ap = dec_key(mp_key[r]);
    float an = dec_key(mn_key[r]);
    s1 += fmaxf(0.5f + ap - an, 0.f);
    s2 += fmaxf(0.8f - ap, 0.f);
    s3 += fmaxf(an - 0.4f, 0.f);
    s4 += ce_row[r];
  }
#pragma unroll
  for (int s = 1; s < 64; s <<= 1) {
    s1 += __shfl_xor(s1, s, 64);
    s2 += __shfl_xor(s2, s, 64);
    s3 += __shfl_xor(s3, s, 64);
    s4 += __shfl_xor(s4, s, 64);
  }
  const int wv = threadIdx.x >> 6;
  if ((threadIdx.x & 63) == 0) {
    red[0][wv] = s1; red[1][wv] = s2; red[2][wv] = s3; red[3][wv] = s4;
  }
  __syncthreads();
  if (threadIdx.x == 0) {
    float t = 0.f;
#pragma unroll
    for (int c = 0; c < 4; ++c) {
      float tc = 0.f;
#pragma unroll
      for (int w = 0; w < 16; ++w) tc += red[c][w];
      t += tc;
    }
    out[0] = t * (1.0f / N_ROWS);
  }
}

extern "C" void kernel_launch(void* const* d_in, const int* in_sizes, int n_in,
                              void* d_out, int out_size, void* d_ws, size_t ws_size,
                              hipStream_t stream) {
  const float* x   = (const float*)d_in[0];
  const int*   tgt = (const int*)d_in[1];
  char* ws = (char*)d_ws;

  unsigned short* xs     = (unsigned short*)ws;                           // 2 MB sorted bf16
  unsigned*       mp_key = (unsigned*)(ws + (2u << 20));                  // 64 KB
  unsigned*       mn_key = (unsigned*)(ws + (2u << 20) + (64u << 10));    // 64 KB
  float*          ce_row = (float*)(ws + (2u << 20) + (128u << 10));      // 64 KB
  int*            perm   = (int*)(ws + (2u << 20) + (192u << 10));        // 64 KB
  int*            ts     = (int*)(ws + (2u << 20) + (256u << 10));        // 64 KB
  int*            cstart = (int*)(ws + (2u << 20) + (320u << 10));        // 65*4 B
  float*          out    = (float*)d_out;

  perm_kernel<<<1, 1024, 0, stream>>>(tgt, perm, ts, cstart, mp_key, mn_key);
  prep_kernel<<<N_ROWS / 4, 256, 0, stream>>>(x, tgt, perm, xs, ce_row);
  mine_kernel<<<64 * 32, 256, 0, stream>>>(xs, ts, cstart, mp_key, mn_key);
  finalize_kernel<<<1, 1024, 0, stream>>>(mp_key, mn_key, ce_row, out);
}